// Round 13
// baseline (277.351 us; speedup 1.0000x reference)
//
#include <hip/hip_runtime.h>
#include <hip/hip_bf16.h>

#define NH 128   // hidden
#define NC 384   // edge feature dim
#define NK 32    // neighbors

typedef __attribute__((ext_vector_type(8))) short short8v;   // 8 bf16
typedef __attribute__((ext_vector_type(4))) float f32x4;

#define MFMA16(a, b, c) __builtin_amdgcn_mfma_f32_16x16x32_bf16((a), (b), (c), 0, 0, 0)

__device__ __forceinline__ ushort f2bf(float x) {
  __hip_bfloat16 h = __float2bfloat16(x);   // RNE; packs to v_cvt_pk_bf16_f32
  ushort u;
  __builtin_memcpy(&u, &h, 2);
  return u;
}

__device__ __forceinline__ short8v ld8(const ushort* p) {
  return *reinterpret_cast<const short8v*>(p);
}
__device__ __forceinline__ void st8(ushort* p, short8v v) {
  *reinterpret_cast<short8v*>(p) = v;
}

__device__ __forceinline__ short8v pack8(float4 a, float4 b) {
  short8v v;
  v[0] = (short)f2bf(a.x); v[1] = (short)f2bf(a.y);
  v[2] = (short)f2bf(a.z); v[3] = (short)f2bf(a.w);
  v[4] = (short)f2bf(b.x); v[5] = (short)f2bf(b.y);
  v[6] = (short)f2bf(b.z); v[7] = (short)f2bf(b.w);
  return v;
}

// gelu(x) = x * sigmoid(x*(1.5958 + 0.07136 x^2)); |err| vs erf-GELU < 1e-3
__device__ __forceinline__ float gelu_f(float x) {
  float x2 = x * x;
  float m = __builtin_fmaf(0.07135481283f, x2, 1.595769122f);
  float e = __expf(-x * m);
  return x * __builtin_amdgcn_rcpf(1.0f + e);
}

// barrier that does NOT drain vmcnt: LDS writes visible, global loads stay in
// flight. sched_barrier(0) pins codegen around the inline-asm waitcnt (rule 18).
__device__ __forceinline__ void lds_barrier() {
  asm volatile("s_waitcnt lgkmcnt(0)" ::: "memory");
  __builtin_amdgcn_sched_barrier(0);
  __builtin_amdgcn_s_barrier();
}

// async 16B HBM -> LDS (no VGPR data path); LDS dest = wave-uniform base +
// lane*16 (HW rule, m104); global src is per-lane.
__device__ __forceinline__ void gload_lds16(const float* g, float* l) {
  __builtin_amdgcn_global_load_lds(
      (const __attribute__((address_space(1))) unsigned int*)g,
      (__attribute__((address_space(3))) unsigned int*)l, 16, 0, 0);
}

// ---------------------------------------------------------------------------
// Weight packing: src row-major [k][col] f32 -> bf16 [k/8][col][k%8]
// ushort offsets: W1p 0 (64Ki), W2p 65536 (16Ki), W3p 81920 (16Ki),
// Winp 98304 (64Ki), Woutp 163840 (64Ki). Total 448 KB.
// ---------------------------------------------------------------------------
__global__ __launch_bounds__(256) void pack_w(
    const float* __restrict__ W1, const float* __restrict__ W2,
    const float* __restrict__ W3, const float* __restrict__ Win,
    const float* __restrict__ Wout, ushort* __restrict__ ws) {
  int id = blockIdx.x * 256 + threadIdx.x;
  if (id < 65536) {                       // W1: K=512, ncol=128
    int t = id, k = t >> 7, c = t & 127;
    ws[(((k >> 3) << 7) + c) * 8 + (k & 7)] = f2bf(W1[t]);
  } else if (id < 81920) {                // W2
    int t = id - 65536, k = t >> 7, c = t & 127;
    ws[65536 + (((k >> 3) << 7) + c) * 8 + (k & 7)] = f2bf(W2[t]);
  } else if (id < 98304) {                // W3
    int t = id - 81920, k = t >> 7, c = t & 127;
    ws[81920 + (((k >> 3) << 7) + c) * 8 + (k & 7)] = f2bf(W3[t]);
  } else if (id < 163840) {               // Win: K=128, ncol=512
    int t = id - 98304, k = t >> 9, c = t & 511;
    ws[98304 + (((k >> 3) << 9) + c) * 8 + (k & 7)] = f2bf(Win[t]);
  } else {                                // Wout: K=512, ncol=128
    int t = id - 163840, k = t >> 7, c = t & 127;
    ws[163840 + (((k >> 3) << 7) + c) * 8 + (k & 7)] = f2bf(Wout[t]);
  }
}

// ---------- msg6 helpers ----------

// issue global loads of 64-col chunk c of pair p: 8 f32/thread (2 dwordx4)
__device__ __forceinline__ void issue_chunk(const float* __restrict__ hE,
    int p, int c, int tid, int N, float4& a, float4& b) {
  const int r = tid >> 3;              // row 0..63 (node*32 + edge)
  const int cb = (tid & 7) * 8;        // col base within chunk
  const int node = r >> 5, e = r & 31;
  int n = 2 * p + node;
  if (n >= N) n = 0;
  const float* g = hE + ((size_t)n * NK + e) * NC + c * 64 + cb;
  const float4* gp = reinterpret_cast<const float4*>(g);
  a = gp[0];
  b = gp[1];
}

// convert staged regs -> 64x64 bf16 tile (granule XOR-swizzled)
__device__ __forceinline__ void convert_regs(ushort* __restrict__ sC, int tid,
    float4 a, float4 b, bool zz) {
  const int r = tid >> 3, cg = tid & 7;
  short8v v = zz ? (short8v){0, 0, 0, 0, 0, 0, 0, 0} : pack8(a, b);
  st8(sC + r * 64 + ((cg ^ (r & 7)) << 3), v);
}

// convert prefetched f32 chunk in LDS -> 64x64 bf16 tile (swizzled)
__device__ __forceinline__ void convert_lds(const float* __restrict__ sPre,
    ushort* __restrict__ sC, int tid, bool zz) {
  const int r = tid >> 3, cg = tid & 7;
  const float4* sp = reinterpret_cast<const float4*>(sPre + r * 64 + cg * 8);
  short8v v = zz ? (short8v){0, 0, 0, 0, 0, 0, 0, 0} : pack8(sp[0], sp[1]);
  st8(sC + r * 64 + ((cg ^ (r & 7)) << 3), v);
}

// async prefetch of pair p: chunks c0,c1 (2x16KB f32), hV (1KB), mAtt (256B)
__device__ __forceinline__ void prefetch_pair(const float* __restrict__ hE,
    const float* __restrict__ hV, const float* __restrict__ mAtt,
    float* __restrict__ sPre0, float* __restrict__ sPre1,
    float* __restrict__ sPHV, float* __restrict__ sPMA,
    int p, int tid, int N) {
  const int w = tid >> 6, l = tid & 63;
#pragma unroll
  for (int c = 0; c < 2; ++c) {
    float* dst = c ? sPre1 : sPre0;
#pragma unroll
    for (int j = 0; j < 2; ++j) {
      const int base16 = (j * 8 + w) * 64;      // 16B units, wave-uniform
      const int fidx = (base16 + l) * 4;        // this lane's f32 index
      const int row = fidx >> 6, col = fidx & 63;
      const int node = row >> 5, e = row & 31;
      int n = 2 * p + node;
      if (n >= N) n = 0;
      gload_lds16(hE + ((size_t)n * NK + e) * NC + c * 64 + col,
                  dst + base16 * 4);
    }
  }
  if (tid < 64) {              // hV: 2x128 f32 contiguous; lane l -> f32[4l..)
    const int node = tid >> 5, c4 = (tid & 31) * 4;
    int n = 2 * p + node;
    if (n >= N) n = 0;
    gload_lds16(hV + (size_t)n * NH + c4, sPHV);
  } else if (tid < 80) {       // mAtt: 2x32 f32; lanes 0..15 of wave 1
    const int l2 = tid - 64;
    const int node = l2 >> 3, e4 = (l2 & 7) * 4;
    int n = 2 * p + node;
    if (n >= N) n = 0;
    gload_lds16(mAtt + (size_t)n * NK + e4, sPMA);
  }
}

// MFMA over one 64-col chunk j (k global [128+j*64, 128+(j+1)*64))
__device__ __forceinline__ void mfma_chunk64(const ushort* __restrict__ sC,
    const ushort* __restrict__ W1p, int j, f32x4 acc[4],
    int g, int lr, int outcol) {
#pragma unroll
  for (int jj = 0; jj < 2; ++jj) {
    short8v bfr = ld8(W1p + (((16 + j * 8 + jj * 4 + g) * 128) + outcol) * 8);
    const int akg = jj * 4 + g;
#pragma unroll
    for (int rt = 0; rt < 4; ++rt) {
      const int row = rt * 16 + lr;
      short8v af = ld8(sC + row * 64 + ((akg ^ (row & 7)) << 3));
      acc[rt] = MFMA16(af, bfr, acc[rt]);
    }
  }
}

// 128-wide helpers for H1/H2 (granule space 16, row&15 swizzle)
__device__ __forceinline__ void mfma_chunk(const ushort* __restrict__ buf,
    const ushort* __restrict__ Wp, int ktBase, f32x4 acc[4],
    int g, int lr, int outcol) {
#pragma unroll
  for (int j = 0; j < 4; ++j) {
    short8v bfr = ld8(Wp + (((ktBase + j) * 4 + g) * 128 + outcol) * 8);
    const int kcg = j * 4 + g;
#pragma unroll
    for (int rt = 0; rt < 4; ++rt) {
      const int row = rt * 16 + lr;
      short8v af = ld8(buf + row * 128 + ((kcg ^ (row & 15)) << 3));
      acc[rt] = MFMA16(af, bfr, acc[rt]);
    }
  }
}

__device__ __forceinline__ void epi_store(ushort* __restrict__ buf,
    const f32x4 acc[4], float bs, int outcol, int g) {
#pragma unroll
  for (int rt = 0; rt < 4; ++rt)
#pragma unroll
    for (int i = 0; i < 4; ++i) {
      const int rr = rt * 16 + g * 4 + i;
      buf[rr * 128 + ((((outcol >> 3) ^ (rr & 15)) << 3) | (outcol & 7))] =
          f2bf(gelu_f(acc[rt][i] + bs));
    }
}

// ---------------------------------------------------------------------------
// Message kernel v6: PERSISTENT, 512 blocks x 512 threads, ~10 pairs each.
// msg3's validated in-pair pipeline (6x64-col chunks, 2 reg banks, lgkm-only
// barriers) + LDS-target prefetch of the NEXT pair (global_load_lds: c0,c1,
// hV, mAtt -> 34.5KB, ZERO registers) issued after layer-3's weight loads.
// Biases/g1/be1 hoisted to regs; current hV/mAtt read from prefetch LDS ->
// no in-tail global read forces a vmcnt(0) drain of the prefetch. The only
// intended drain is the loop-top __syncthreads. LDS ~70KB -> 2 blocks/CU.
// ---------------------------------------------------------------------------
__global__ __launch_bounds__(512, 4) void msg6(
    const float* __restrict__ hV, const float* __restrict__ hE,
    const float* __restrict__ mAtt, const ushort* __restrict__ wsu,
    const float* __restrict__ b1, const float* __restrict__ b2,
    const float* __restrict__ b3, const float* __restrict__ g1,
    const float* __restrict__ be1, float* __restrict__ hmidf,
    ushort* __restrict__ hmidb, int N) {
  const ushort* W1p = wsu;
  const ushort* W2p = wsu + 65536;
  const ushort* W3p = wsu + 81920;

  __shared__ float  sPre[2][4096];   // 32KB: next pair's c0,c1 (f32, linear)
  __shared__ float  sPHV[2][256];    // 2KB: hV f32, parity-buffered
  __shared__ float  sPMA[2][64];     // 512B: mAtt f32, parity-buffered
  __shared__ ushort sC[2][4096];     // 16KB bf16 chunk tiles; reused as H1
  __shared__ ushort sH2[8192];       // 16KB H2
  __shared__ ushort sHV[256];        // 2 nodes x 128 bf16
  __shared__ float  sDh[256];
  __shared__ float  sRed[16];

  const int tid = threadIdx.x;
  const int w = tid >> 6, lane = tid & 63;
  const int g = lane >> 4, lr = lane & 15;
  const int outcol = (w << 4) + lr;

  const int pairs = (N + 1) >> 1;
  const int stride = gridDim.x;
  const int bId = blockIdx.x;
  const int T = (pairs - bId + stride - 1) / stride;   // grid <= pairs

  // hoisted loop-invariant scalars (kills in-tail global scalar loads)
  const float b1c = b1[outcol], b2c = b2[outcol], b3c = b3[outcol];
  const float g1c = g1[tid & 127], be1c = be1[tid & 127];

  float4 eA, eB, oA, oB;   // two 8-f32 staging banks (in-pair chunks c2..c5)

  // ---- prologue: async prefetch of pair bId into parity-0 buffers ----
  if (T > 0)
    prefetch_pair(hE, hV, mAtt, sPre[0], sPre[1], sPHV[0], sPMA[0], bId, tid, N);

  f32x4 acc[4];

  for (int t = 0; t < T; ++t) {
    const int p = bId + t * stride;
    const int par = t & 1, nxt = par ^ 1;
    const bool zz = (2 * p + (tid >> 8)) >= N;        // staging-row validity
    const int pn = bId + (t + 1) * stride;
    const int pnc = pn < pairs ? pn : bId;            // clamped next pair

    __syncthreads();   // the ONE vmcnt drain: prefetched data now in LDS

    // ---- convert c0 (sPre[0] -> sC[0]); hV f32 -> bf16 sHV ----
    convert_lds(sPre[0], sC[0], tid, zz);
    if (tid < 32) {
      const float4* hp = reinterpret_cast<const float4*>(&sPHV[par][tid * 8]);
      st8(sHV + tid * 8, pack8(hp[0], hp[1]));
    }
    lds_barrier();

#pragma unroll
    for (int rt = 0; rt < 4; ++rt) acc[rt] = (f32x4){0.f, 0.f, 0.f, 0.f};

    // ===== phase 0: issue c2; hV part + chunk0; convert c1 (sPre[1]) =====
    issue_chunk(hE, p, 2, tid, N, eA, eB);
#pragma unroll
    for (int kt = 0; kt < 4; ++kt) {
      short8v bfr = ld8(W1p + ((kt * 4 + g) * 128 + outcol) * 8);
      short8v a0 = ld8(sHV + kt * 32 + g * 8);
      short8v a1 = ld8(sHV + 128 + kt * 32 + g * 8);
      acc[0] = MFMA16(a0, bfr, acc[0]);
      acc[1] = MFMA16(a0, bfr, acc[1]);
      acc[2] = MFMA16(a1, bfr, acc[2]);
      acc[3] = MFMA16(a1, bfr, acc[3]);
    }
    mfma_chunk64(sC[0], W1p, 0, acc, g, lr, outcol);
    convert_lds(sPre[1], sC[1], tid, zz);
    lds_barrier();

    // ===== phase 1: issue c3; chunk1; convert c2 (regs) =====
    issue_chunk(hE, p, 3, tid, N, oA, oB);
    mfma_chunk64(sC[1], W1p, 1, acc, g, lr, outcol);
    convert_regs(sC[0], tid, eA, eB, zz);
    lds_barrier();

    // ===== phase 2: issue c4; chunk2; convert c3 =====
    issue_chunk(hE, p, 4, tid, N, eA, eB);
    mfma_chunk64(sC[0], W1p, 2, acc, g, lr, outcol);
    convert_regs(sC[1], tid, oA, oB, zz);
    lds_barrier();

    // ===== phase 3: issue c5; chunk3; convert c4 =====
    issue_chunk(hE, p, 5, tid, N, oA, oB);
    mfma_chunk64(sC[1], W1p, 3, acc, g, lr, outcol);
    convert_regs(sC[0], tid, eA, eB, zz);
    lds_barrier();

    // ===== phase 4: chunk4; convert c5 =====
    mfma_chunk64(sC[0], W1p, 4, acc, g, lr, outcol);
    convert_regs(sC[1], tid, oA, oB, zz);
    lds_barrier();

    // ===== phase 5: chunk5 =====
    mfma_chunk64(sC[1], W1p, 5, acc, g, lr, outcol);
    lds_barrier();                      // all chunk reads done before H1 overwrite

    // ===== layer-1 epilogue: H1 -> sC region (as [64][128]) =====
    ushort* sH1 = &sC[0][0];
    epi_store(sH1, acc, b1c, outcol, g);
    lds_barrier();

    // ===== layer 2: H1 -> H2 =====
#pragma unroll
    for (int rt = 0; rt < 4; ++rt) acc[rt] = (f32x4){0.f, 0.f, 0.f, 0.f};
    mfma_chunk(sH1, W2p, 0, acc, g, lr, outcol);
    epi_store(sH2, acc, b2c, outcol, g);
    lds_barrier();

    // ===== layer 3: H2 MFMA; THEN prefetch next pair; then edge-sum =====
#pragma unroll
    for (int rt = 0; rt < 4; ++rt) acc[rt] = (f32x4){0.f, 0.f, 0.f, 0.f};
    mfma_chunk(sH2, W3p, 0, acc, g, lr, outcol);
    // all weight loads of this iteration are issued; prefetch can't be
    // drained by a later vmcnt-to-use (tail is LDS/reg/stores only).
    prefetch_pair(hE, hV, mAtt, sPre[0], sPre[1], sPHV[nxt], sPMA[nxt],
                  pnc, tid, N);
    {
      float ns0 = 0.f, ns1 = 0.f;
#pragma unroll
      for (int rt = 0; rt < 4; ++rt) {
        const int nd = rt >> 1;
        float s = 0.f;
#pragma unroll
        for (int i = 0; i < 4; ++i) {
          const int e2 = (rt & 1) * 16 + g * 4 + i;
          s += (acc[rt][i] + b3c) * sPMA[par][nd * 32 + e2];
        }
        s += __shfl_xor(s, 16, 64);
        s += __shfl_xor(s, 32, 64);
        if (rt < 2) ns0 += s; else ns1 += s;
      }
      if (g == 0) { sDh[outcol] = ns0; sDh[128 + outcol] = ns1; }
    }
    lds_barrier();

    // ===== LN1 part 1 (hV f32 from prefetch buffer — no global read) =====
    float x_ln = 0.f;
    if (tid < 256) {
      const int nd = tid >> 7, i = tid & 127;
      x_ln = sPHV[par][nd * 128 + i] + sDh[nd * NH + i] * (1.f / 30.f);
      float s = x_ln, qv = x_ln * x_ln;
#pragma unroll
      for (int d = 1; d < 64; d <<= 1) {
        s += __shfl_xor(s, d, 64);
        qv += __shfl_xor(qv, d, 64);
      }
      if (lane == 0) { sRed[w * 2] = s; sRed[w * 2 + 1] = qv; }
    }
    lds_barrier();

    // ===== LN1 part 2: write h_mid =====
    if (tid < 256) {
      const int nd = tid >> 7, i = tid & 127;
      const int gn = 2 * p + nd;
      if (gn < N) {
        const int wb = nd * 2;
        const float s = sRed[wb * 2] + sRed[wb * 2 + 2];
        const float qv = sRed[wb * 2 + 1] + sRed[wb * 2 + 3];
        const float mean = s * (1.f / 128.f);
        const float var = qv * (1.f / 128.f) - mean * mean;
        const float y = (x_ln - mean) * rsqrtf(var + 1e-5f) * g1c + be1c;
        hmidf[(size_t)gn * NH + i] = y;
        hmidb[(size_t)gn * NH + i] = f2bf(y);
      }
    }
    // next iteration's __syncthreads makes sDh/sRed reuse + prefetch safe
  }
}

// ---------------------------------------------------------------------------
// FFN kernel: 16 nodes / block (625 blocks), 256 threads (4 waves).
// ---------------------------------------------------------------------------
__global__ __launch_bounds__(256, 4) void ffn_kernel(
    const ushort* __restrict__ wsu, const float* __restrict__ binf,
    const float* __restrict__ boutf, const float* __restrict__ g2,
    const float* __restrict__ be2, const float* __restrict__ maskV,
    const float* __restrict__ hmidf, const ushort* __restrict__ hmidb,
    float* __restrict__ out, int N) {
  const ushort* Winp = wsu + 98304;
  const ushort* Woutp = wsu + 163840;

  __shared__ ushort sX[16 * 128];     // 4KB
  __shared__ ushort sHf[16 * 512];    // 16KB
  __shared__ float  sY[16 * 132];     // 8.25KB

  const int tid = threadIdx.x;
  const int w = tid >> 6, lane = tid & 63;
  const int g = lane >> 4, lr = lane & 15;
  const int n0 = blockIdx.x * 16;

  // stage h_mid (bf16) -> sX swizzled (256 chunks, one per thread)
  {
    const int rr = tid >> 4, c8 = tid & 15;
    const int n = n0 + rr;
    short8v v = {0, 0, 0, 0, 0, 0, 0, 0};
    if (n < N) v = ld8(hmidb + (size_t)n * NH + c8 * 8);
    st8(sX + rr * 128 + ((c8 ^ (rr & 15)) << 3), v);
  }
  __syncthreads();

  // -------- layer in: [16,128] @ Win -> gelu -> sHf [16,512] --------
#pragma unroll
  for (int ct8 = 0; ct8 < 8; ++ct8) {
    const int col = (w * 8 + ct8) * 16 + lr;
    f32x4 a0acc = (f32x4){0.f, 0.f, 0.f, 0.f};
#pragma unroll
    for (int kt = 0; kt < 4; ++kt) {
      short8v b = ld8(Winp + ((kt * 4 + g) * 512 + col) * 8);
      const int kcg = kt * 4 + g;
      const int r0 = lr;
      short8v a0 = ld8(sX + r0 * 128 + ((kcg ^ (r0 & 15)) << 3));
      a0acc = MFMA16(a0, b, a0acc);
    }
    const float bi = binf[col];
#pragma unroll
    for (int i = 0; i < 4; ++i) {
      const int rr = g * 4 + i;
      const float v0 = gelu_f(a0acc[i] + bi);
      sHf[rr * 512 + ((((col >> 3) ^ (rr & 15)) << 3) | (col & 7))] = f2bf(v0);
    }
  }
  __syncthreads();

  // -------- layer out: [16,512] @ Wout (wave w -> cols [w*32, w*32+32)) -----
  f32x4 o0 = (f32x4){0.f, 0.f, 0.f, 0.f}, o1 = o0;
#pragma unroll
  for (int kt = 0; kt < 16; ++kt) {
    const int kcg = kt * 4 + g;                 // [0,64)
    const int c0 = (2 * w) * 16 + lr, c1 = (2 * w + 1) * 16 + lr;
    short8v b0 = ld8(Woutp + (kcg * 128 + c0) * 8);
    short8v b1 = ld8(Woutp + (kcg * 128 + c1) * 8);
    const int r0 = lr;
    short8v a0 = ld8(sHf + r0 * 512 + ((kcg ^ (r0 & 15)) << 3));
    o0 = MFMA16(a0, b0, o0);
    o1 = MFMA16(a0, b1, o1);
  }
  // epilogue: + bias + residual -> sY
#pragma unroll
  for (int ct = 0; ct < 2; ++ct) {
    const int col = (2 * w + ct) * 16 + lr;
    const float bo = boutf[col];
    const f32x4 oo = ct ? o1 : o0;
#pragma unroll
    for (int i = 0; i < 4; ++i) {
      const int rr = g * 4 + i;
      const int n = n0 + rr;
      const float resid = (n < N) ? hmidf[(size_t)n * NH + col] : 0.f;
      sY[rr * 132 + col] = oo[i] + bo + resid;
    }
  }
  __syncthreads();

  // -------- LN2 + mask + store (16 threads per row, 8 cols each) --------
  {
    const int rr = tid >> 4, qq = tid & 15;
    const int n = n0 + rr;
    float vals[8];
    float s = 0.f, qs = 0.f;
    const float* yr = sY + rr * 132 + qq * 8;
#pragma unroll
    for (int j = 0; j < 8; ++j) { float x = yr[j]; vals[j] = x; s += x; qs += x * x; }
    s += __shfl_xor(s, 1, 64);  qs += __shfl_xor(qs, 1, 64);
    s += __shfl_xor(s, 2, 64);  qs += __shfl_xor(qs, 2, 64);
    s += __shfl_xor(s, 4, 64);  qs += __shfl_xor(qs, 4, 64);
    s += __shfl_xor(s, 8, 64);  qs += __shfl_xor(qs, 8, 64);
    const float mean = s * (1.f / 128.f);
    const float var = qs * (1.f / 128.f) - mean * mean;
    const float rs = rsqrtf(var + 1e-5f);
    if (n < N) {
      const float mv = maskV[n];
#pragma unroll
      for (int j = 0; j < 8; ++j) {
        const int col = qq * 8 + j;
        out[(size_t)n * NH + col] = ((vals[j] - mean) * rs * g2[col] + be2[col]) * mv;
      }
    }
  }
}

extern "C" void kernel_launch(void* const* d_in, const int* in_sizes, int n_in,
                              void* d_out, int out_size, void* d_ws, size_t ws_size,
                              hipStream_t stream) {
  const float* hV   = (const float*)d_in[0];
  const float* hE   = (const float*)d_in[1];
  const float* mV   = (const float*)d_in[2];
  const float* mAtt = (const float*)d_in[3];
  const float* W1   = (const float*)d_in[4];
  const float* b1   = (const float*)d_in[5];
  const float* W2   = (const float*)d_in[6];
  const float* b2   = (const float*)d_in[7];
  const float* W3   = (const float*)d_in[8];
  const float* b3   = (const float*)d_in[9];
  const float* g1   = (const float*)d_in[10];
  const float* be1  = (const float*)d_in[11];
  const float* Win  = (const float*)d_in[12];
  const float* binf = (const float*)d_in[13];
  const float* Wout = (const float*)d_in[14];
  const float* bout = (const float*)d_in[15];
  const float* g2   = (const float*)d_in[16];
  const float* be2  = (const float*)d_in[17];

  const int N = in_sizes[0] / NH;

  ushort* wsu = (ushort*)d_ws;                         // packed weights: 448 KB
  float*  hmidf = (float*)((char*)d_ws + 458752);      // N*128 f32
  ushort* hmidb = (ushort*)((char*)d_ws + 458752 + (size_t)N * NH * 4);  // N*128 bf16

  pack_w<<<896, 256, 0, stream>>>(W1, W2, W3, Win, Wout, wsu);

  const int pairs = (N + 1) / 2;
  const int grid = pairs < 512 ? pairs : 512;
  msg6<<<grid, 512, 0, stream>>>(hV, hE, mAtt, wsu, b1, b2, b3, g1, be1,
                                 hmidf, hmidb, N);
  ffn_kernel<<<(N + 15) / 16, 256, 0, stream>>>(wsu, binf, bout, g2, be2, mV,
                                                hmidf, hmidb, (float*)d_out, N);
  (void)n_in; (void)out_size; (void)ws_size;
}

// Round 14
// 248.489 us; speedup vs baseline: 1.1162x; 1.1162x over previous
//
#include <hip/hip_runtime.h>
#include <hip/hip_bf16.h>

#define NH 128   // hidden
#define NC 384   // edge feature dim
#define NK 32    // neighbors

typedef __attribute__((ext_vector_type(8))) short short8v;   // 8 bf16
typedef __attribute__((ext_vector_type(4))) float f32x4;

#define MFMA16(a, b, c) __builtin_amdgcn_mfma_f32_16x16x32_bf16((a), (b), (c), 0, 0, 0)

__device__ __forceinline__ ushort f2bf(float x) {
  __hip_bfloat16 h = __float2bfloat16(x);   // RNE; packs to v_cvt_pk_bf16_f32
  ushort u;
  __builtin_memcpy(&u, &h, 2);
  return u;
}

__device__ __forceinline__ short8v ld8(const ushort* p) {
  return *reinterpret_cast<const short8v*>(p);
}
__device__ __forceinline__ void st8(ushort* p, short8v v) {
  *reinterpret_cast<short8v*>(p) = v;
}

__device__ __forceinline__ short8v pack8(float4 a, float4 b) {
  short8v v;
  v[0] = (short)f2bf(a.x); v[1] = (short)f2bf(a.y);
  v[2] = (short)f2bf(a.z); v[3] = (short)f2bf(a.w);
  v[4] = (short)f2bf(b.x); v[5] = (short)f2bf(b.y);
  v[6] = (short)f2bf(b.z); v[7] = (short)f2bf(b.w);
  return v;
}

// gelu(x) = x * sigmoid(x*(1.5958 + 0.07136 x^2)); |err| vs erf-GELU < 1e-3
__device__ __forceinline__ float gelu_f(float x) {
  float x2 = x * x;
  float m = __builtin_fmaf(0.07135481283f, x2, 1.595769122f);
  float e = __expf(-x * m);
  return x * __builtin_amdgcn_rcpf(1.0f + e);
}

// barrier that does NOT drain vmcnt: LDS writes visible, global loads stay in
// flight. sched_barrier(0) pins codegen around the inline-asm waitcnt (rule 18).
__device__ __forceinline__ void lds_barrier() {
  asm volatile("s_waitcnt lgkmcnt(0)" ::: "memory");
  __builtin_amdgcn_sched_barrier(0);
  __builtin_amdgcn_s_barrier();
}

// ---------------------------------------------------------------------------
// Weight packing: src row-major [k][col] f32 -> bf16 [k/8][col][k%8]
// ushort offsets: W1p 0 (64Ki), W2p 65536 (16Ki), W3p 81920 (16Ki),
// Winp 98304 (64Ki), Woutp 163840 (64Ki). Total 448 KB.
// ---------------------------------------------------------------------------
__global__ __launch_bounds__(256) void pack_w(
    const float* __restrict__ W1, const float* __restrict__ W2,
    const float* __restrict__ W3, const float* __restrict__ Win,
    const float* __restrict__ Wout, ushort* __restrict__ ws) {
  int id = blockIdx.x * 256 + threadIdx.x;
  if (id < 65536) {                       // W1: K=512, ncol=128
    int t = id, k = t >> 7, c = t & 127;
    ws[(((k >> 3) << 7) + c) * 8 + (k & 7)] = f2bf(W1[t]);
  } else if (id < 81920) {                // W2
    int t = id - 65536, k = t >> 7, c = t & 127;
    ws[65536 + (((k >> 3) << 7) + c) * 8 + (k & 7)] = f2bf(W2[t]);
  } else if (id < 98304) {                // W3
    int t = id - 81920, k = t >> 7, c = t & 127;
    ws[81920 + (((k >> 3) << 7) + c) * 8 + (k & 7)] = f2bf(W3[t]);
  } else if (id < 163840) {               // Win: K=128, ncol=512
    int t = id - 98304, k = t >> 9, c = t & 511;
    ws[98304 + (((k >> 3) << 9) + c) * 8 + (k & 7)] = f2bf(Win[t]);
  } else {                                // Wout: K=512, ncol=128
    int t = id - 163840, k = t >> 7, c = t & 127;
    ws[163840 + (((k >> 3) << 7) + c) * 8 + (k & 7)] = f2bf(Wout[t]);
  }
}

// ---------- msg helpers (validated msg3 set) ----------

// issue global loads of 64-col chunk c of pair p: 8 f32/thread (2 dwordx4)
__device__ __forceinline__ void issue_chunk(const float* __restrict__ hE,
    int p, int c, int tid, int N, float4& a, float4& b) {
  const int r = tid >> 3;              // row 0..63 (node*32 + edge)
  const int cb = (tid & 7) * 8;        // col base within chunk
  const int node = r >> 5, e = r & 31;
  int n = 2 * p + node;
  if (n >= N) n = 0;
  const float* g = hE + ((size_t)n * NK + e) * NC + c * 64 + cb;
  const float4* gp = reinterpret_cast<const float4*>(g);
  a = gp[0];
  b = gp[1];
}

// convert staged regs -> 64x64 bf16 tile (granule XOR-swizzled)
__device__ __forceinline__ void convert_regs(ushort* __restrict__ sC, int tid,
    float4 a, float4 b, bool zz) {
  const int r = tid >> 3, cg = tid & 7;
  short8v v = zz ? (short8v){0, 0, 0, 0, 0, 0, 0, 0} : pack8(a, b);
  st8(sC + r * 64 + ((cg ^ (r & 7)) << 3), v);
}

// MFMA over one 64-col chunk j (k global [128+j*64, 128+(j+1)*64))
__device__ __forceinline__ void mfma_chunk64(const ushort* __restrict__ sC,
    const ushort* __restrict__ W1p, int j, f32x4 acc[4],
    int g, int lr, int outcol) {
#pragma unroll
  for (int jj = 0; jj < 2; ++jj) {
    short8v bfr = ld8(W1p + (((16 + j * 8 + jj * 4 + g) * 128) + outcol) * 8);
    const int akg = jj * 4 + g;
#pragma unroll
    for (int rt = 0; rt < 4; ++rt) {
      const int row = rt * 16 + lr;
      short8v af = ld8(sC + row * 64 + ((akg ^ (row & 7)) << 3));
      acc[rt] = MFMA16(af, bfr, acc[rt]);
    }
  }
}

// 128-wide helpers for H1/H2 (granule space 16, row&15 swizzle)
__device__ __forceinline__ void mfma_chunk(const ushort* __restrict__ buf,
    const ushort* __restrict__ Wp, int ktBase, f32x4 acc[4],
    int g, int lr, int outcol) {
#pragma unroll
  for (int j = 0; j < 4; ++j) {
    short8v bfr = ld8(Wp + (((ktBase + j) * 4 + g) * 128 + outcol) * 8);
    const int kcg = j * 4 + g;
#pragma unroll
    for (int rt = 0; rt < 4; ++rt) {
      const int row = rt * 16 + lr;
      short8v af = ld8(buf + row * 128 + ((kcg ^ (row & 15)) << 3));
      acc[rt] = MFMA16(af, bfr, acc[rt]);
    }
  }
}

__device__ __forceinline__ void epi_store(ushort* __restrict__ buf,
    const f32x4 acc[4], const float* __restrict__ bias, int outcol, int g) {
  const float bs = bias[outcol];
#pragma unroll
  for (int rt = 0; rt < 4; ++rt)
#pragma unroll
    for (int i = 0; i < 4; ++i) {
      const int rr = rt * 16 + g * 4 + i;
      buf[rr * 128 + ((((outcol >> 3) ^ (rr & 15)) << 3) | (outcol & 7))] =
          f2bf(gelu_f(acc[rt][i] + bs));
    }
}

// ---------------------------------------------------------------------------
// Message kernel v7: PERSISTENT msg3. 512 blocks x 512 threads, ~10 pairs
// each, with the msg3 per-pair body UNCHANGED (no state lives across the
// tail — loop top re-issues c0/c1 like a fresh prologue). One-time ~6.8us
// s_sleep stagger for blocks with odd (bit0 ^ bit8) breaks the 2-blocks/CU
// convoy: co-resident blocks offset by ~half a lifetime => their tails never
// overlap => HBM stays fed through every tail. Covers both common
// blockIdx->CU mappings (adjacent-pair and +256-stride).
// LDS ~34KB. sC region (16KB) is reused as H1 after layer 1.
// ---------------------------------------------------------------------------
__global__ __launch_bounds__(512, 4) void msg7(
    const float* __restrict__ hV, const float* __restrict__ hE,
    const float* __restrict__ mAtt, const ushort* __restrict__ wsu,
    const float* __restrict__ b1, const float* __restrict__ b2,
    const float* __restrict__ b3, const float* __restrict__ g1,
    const float* __restrict__ be1, float* __restrict__ hmidf,
    ushort* __restrict__ hmidb, int N) {
  const ushort* W1p = wsu;
  const ushort* W2p = wsu + 65536;
  const ushort* W3p = wsu + 81920;

  __shared__ ushort sC[2][4096];    // 2 x 8KB bf16 chunk tiles; reused as H1
  __shared__ ushort sH2[8192];      // 16KB H2
  __shared__ ushort sHV[256];       // 2 nodes x 128 bf16
  __shared__ float  sDh[256];
  __shared__ float  sRed[16];

  const int tid = threadIdx.x;
  const int w = tid >> 6, lane = tid & 63;
  const int g = lane >> 4, lr = lane & 15;
  const int outcol = (w << 4) + lr;

  const int pairs = (N + 1) >> 1;
  const int stride = gridDim.x;
  const int bId = blockIdx.x;
  const int T = (pairs - bId + stride - 1) / stride;   // grid <= pairs

  // one-time de-convoy stagger (~6.8us): offsets this block vs its CU-mate
  if (((bId & 1) ^ ((bId >> 8) & 1)) != 0) {
    __builtin_amdgcn_s_sleep(127);
    __builtin_amdgcn_s_sleep(127);
  }

  f32x4 acc[4];
  float4 eA, eB, oA, oB;   // two 8-f32 staging banks (even/odd chunks)

  for (int t = 0; t < T; ++t) {
    const int p = bId + t * stride;
    const bool zz = (2 * p + (tid >> 8)) >= N;   // staging-row validity

    // ---- prologue (per pair): issue c0/c1; stage hV; convert c0 ----
    issue_chunk(hE, p, 0, tid, N, eA, eB);
    issue_chunk(hE, p, 1, tid, N, oA, oB);
    if (tid < 32) {
      const int nd = tid >> 4, c8 = tid & 15;
      const int n = 2 * p + nd;
      const int ncl = n < N ? n : 0;
      const float4* hp =
          reinterpret_cast<const float4*>(hV + (size_t)ncl * NH + c8 * 8);
      float4 h0 = hp[0], h1 = hp[1];
      if (n >= N) { h0 = (float4){0.f, 0.f, 0.f, 0.f}; h1 = h0; }
      st8(sHV + nd * 128 + c8 * 8, pack8(h0, h1));
    }
    convert_regs(sC[0], tid, eA, eB, zz);   // waits c0 via reg use
    lds_barrier();

#pragma unroll
    for (int rt = 0; rt < 4; ++rt) acc[rt] = (f32x4){0.f, 0.f, 0.f, 0.f};

    // ===== layer-1 hV part (k 0..127) =====
#pragma unroll
    for (int kt = 0; kt < 4; ++kt) {
      short8v bfr = ld8(W1p + ((kt * 4 + g) * 128 + outcol) * 8);
      short8v a0 = ld8(sHV + kt * 32 + g * 8);
      short8v a1 = ld8(sHV + 128 + kt * 32 + g * 8);
      acc[0] = MFMA16(a0, bfr, acc[0]);
      acc[1] = MFMA16(a0, bfr, acc[1]);
      acc[2] = MFMA16(a1, bfr, acc[2]);
      acc[3] = MFMA16(a1, bfr, acc[3]);
    }

    // ===== layer-1 h_E chunks, software-pipelined (lgkm-only barriers) ====
    // j=0: consume c0; convert c1; issue c2
    issue_chunk(hE, p, 2, tid, N, eA, eB);
    mfma_chunk64(sC[0], W1p, 0, acc, g, lr, outcol);
    convert_regs(sC[1], tid, oA, oB, zz);
    lds_barrier();
    // j=1: consume c1; convert c2; issue c3
    issue_chunk(hE, p, 3, tid, N, oA, oB);
    mfma_chunk64(sC[1], W1p, 1, acc, g, lr, outcol);
    convert_regs(sC[0], tid, eA, eB, zz);
    lds_barrier();
    // j=2: consume c2; convert c3; issue c4
    issue_chunk(hE, p, 4, tid, N, eA, eB);
    mfma_chunk64(sC[0], W1p, 2, acc, g, lr, outcol);
    convert_regs(sC[1], tid, oA, oB, zz);
    lds_barrier();
    // j=3: consume c3; convert c4; issue c5
    issue_chunk(hE, p, 5, tid, N, oA, oB);
    mfma_chunk64(sC[1], W1p, 3, acc, g, lr, outcol);
    convert_regs(sC[0], tid, eA, eB, zz);
    lds_barrier();
    // j=4: consume c4; convert c5
    mfma_chunk64(sC[0], W1p, 4, acc, g, lr, outcol);
    convert_regs(sC[1], tid, oA, oB, zz);
    lds_barrier();
    // j=5: consume c5
    mfma_chunk64(sC[1], W1p, 5, acc, g, lr, outcol);
    __syncthreads();

    // ===== layer-1 epilogue: H1 -> sC region (as [64][128]) =====
    ushort* sH1 = &sC[0][0];
    epi_store(sH1, acc, b1, outcol, g);
    __syncthreads();

    // ===== layer 2: H1 -> H2 =====
#pragma unroll
    for (int rt = 0; rt < 4; ++rt) acc[rt] = (f32x4){0.f, 0.f, 0.f, 0.f};
    mfma_chunk(sH1, W2p, 0, acc, g, lr, outcol);
    epi_store(sH2, acc, b2, outcol, g);
    __syncthreads();

    // ===== layer 3: H2 -> masked edge-sum =====
#pragma unroll
    for (int rt = 0; rt < 4; ++rt) acc[rt] = (f32x4){0.f, 0.f, 0.f, 0.f};
    mfma_chunk(sH2, W3p, 0, acc, g, lr, outcol);
    {
      const float bias = b3[outcol];
      float ns0 = 0.f, ns1 = 0.f;
#pragma unroll
      for (int rt = 0; rt < 4; ++rt) {
        const int nd = rt >> 1;
        float s = 0.f;
#pragma unroll
        for (int i = 0; i < 4; ++i) {
          const int e2 = (rt & 1) * 16 + g * 4 + i;
          const float m =
              (2 * p + nd < N) ? mAtt[(size_t)(2 * p + nd) * NK + e2] : 0.f;
          s += (acc[rt][i] + bias) * m;
        }
        s += __shfl_xor(s, 16, 64);
        s += __shfl_xor(s, 32, 64);
        if (rt < 2) ns0 += s; else ns1 += s;
      }
      if (g == 0) { sDh[outcol] = ns0; sDh[128 + outcol] = ns1; }
    }
    __syncthreads();

    // ===== LN1 + h_mid store =====
    float x_ln = 0.f;
    if (tid < 256) {
      const int nd = tid >> 7, i = tid & 127;
      const int gn = 2 * p + nd;
      if (gn < N)
        x_ln = hV[(size_t)gn * NH + i] + sDh[nd * NH + i] * (1.f / 30.f);
      float s = x_ln, qv = x_ln * x_ln;
#pragma unroll
      for (int d = 1; d < 64; d <<= 1) {
        s += __shfl_xor(s, d, 64);
        qv += __shfl_xor(qv, d, 64);
      }
      if (lane == 0) { sRed[w * 2] = s; sRed[w * 2 + 1] = qv; }
    }
    __syncthreads();
    if (tid < 256) {
      const int nd = tid >> 7, i = tid & 127;
      const int gn = 2 * p + nd;
      if (gn < N) {
        const int wb = nd * 2;
        const float s = sRed[wb * 2] + sRed[wb * 2 + 2];
        const float qv = sRed[wb * 2 + 1] + sRed[wb * 2 + 3];
        const float mean = s * (1.f / 128.f);
        const float var = qv * (1.f / 128.f) - mean * mean;
        const float y = (x_ln - mean) * rsqrtf(var + 1e-5f) * g1[i] + be1[i];
        hmidf[(size_t)gn * NH + i] = y;
        hmidb[(size_t)gn * NH + i] = f2bf(y);
      }
    }
    lds_barrier();   // sRed/sDh/sC safe for next iteration's writers
  }
}

// ---------------------------------------------------------------------------
// FFN kernel: 16 nodes / block (625 blocks), 256 threads (4 waves).
// ---------------------------------------------------------------------------
__global__ __launch_bounds__(256, 4) void ffn_kernel(
    const ushort* __restrict__ wsu, const float* __restrict__ binf,
    const float* __restrict__ boutf, const float* __restrict__ g2,
    const float* __restrict__ be2, const float* __restrict__ maskV,
    const float* __restrict__ hmidf, const ushort* __restrict__ hmidb,
    float* __restrict__ out, int N) {
  const ushort* Winp = wsu + 98304;
  const ushort* Woutp = wsu + 163840;

  __shared__ ushort sX[16 * 128];     // 4KB
  __shared__ ushort sHf[16 * 512];    // 16KB
  __shared__ float  sY[16 * 132];     // 8.25KB

  const int tid = threadIdx.x;
  const int w = tid >> 6, lane = tid & 63;
  const int g = lane >> 4, lr = lane & 15;
  const int n0 = blockIdx.x * 16;

  // stage h_mid (bf16) -> sX swizzled (256 chunks, one per thread)
  {
    const int rr = tid >> 4, c8 = tid & 15;
    const int n = n0 + rr;
    short8v v = {0, 0, 0, 0, 0, 0, 0, 0};
    if (n < N) v = ld8(hmidb + (size_t)n * NH + c8 * 8);
    st8(sX + rr * 128 + ((c8 ^ (rr & 15)) << 3), v);
  }
  __syncthreads();

  // -------- layer in: [16,128] @ Win -> gelu -> sHf [16,512] --------
#pragma unroll
  for (int ct8 = 0; ct8 < 8; ++ct8) {
    const int col = (w * 8 + ct8) * 16 + lr;
    f32x4 a0acc = (f32x4){0.f, 0.f, 0.f, 0.f};
#pragma unroll
    for (int kt = 0; kt < 4; ++kt) {
      short8v b = ld8(Winp + ((kt * 4 + g) * 512 + col) * 8);
      const int kcg = kt * 4 + g;
      const int r0 = lr;
      short8v a0 = ld8(sX + r0 * 128 + ((kcg ^ (r0 & 15)) << 3));
      a0acc = MFMA16(a0, b, a0acc);
    }
    const float bi = binf[col];
#pragma unroll
    for (int i = 0; i < 4; ++i) {
      const int rr = g * 4 + i;
      const float v0 = gelu_f(a0acc[i] + bi);
      sHf[rr * 512 + ((((col >> 3) ^ (rr & 15)) << 3) | (col & 7))] = f2bf(v0);
    }
  }
  __syncthreads();

  // -------- layer out: [16,512] @ Wout (wave w -> cols [w*32, w*32+32)) -----
  f32x4 o0 = (f32x4){0.f, 0.f, 0.f, 0.f}, o1 = o0;
#pragma unroll
  for (int kt = 0; kt < 16; ++kt) {
    const int kcg = kt * 4 + g;                 // [0,64)
    const int c0 = (2 * w) * 16 + lr, c1 = (2 * w + 1) * 16 + lr;
    short8v b0 = ld8(Woutp + (kcg * 128 + c0) * 8);
    short8v b1 = ld8(Woutp + (kcg * 128 + c1) * 8);
    const int r0 = lr;
    short8v a0 = ld8(sHf + r0 * 512 + ((kcg ^ (r0 & 15)) << 3));
    o0 = MFMA16(a0, b0, o0);
    o1 = MFMA16(a0, b1, o1);
  }
  // epilogue: + bias + residual -> sY
#pragma unroll
  for (int ct = 0; ct < 2; ++ct) {
    const int col = (2 * w + ct) * 16 + lr;
    const float bo = boutf[col];
    const f32x4 oo = ct ? o1 : o0;
#pragma unroll
    for (int i = 0; i < 4; ++i) {
      const int rr = g * 4 + i;
      const int n = n0 + rr;
      const float resid = (n < N) ? hmidf[(size_t)n * NH + col] : 0.f;
      sY[rr * 132 + col] = oo[i] + bo + resid;
    }
  }
  __syncthreads();

  // -------- LN2 + mask + store (16 threads per row, 8 cols each) --------
  {
    const int rr = tid >> 4, qq = tid & 15;
    const int n = n0 + rr;
    float vals[8];
    float s = 0.f, qs = 0.f;
    const float* yr = sY + rr * 132 + qq * 8;
#pragma unroll
    for (int j = 0; j < 8; ++j) { float x = yr[j]; vals[j] = x; s += x; qs += x * x; }
    s += __shfl_xor(s, 1, 64);  qs += __shfl_xor(qs, 1, 64);
    s += __shfl_xor(s, 2, 64);  qs += __shfl_xor(qs, 2, 64);
    s += __shfl_xor(s, 4, 64);  qs += __shfl_xor(qs, 4, 64);
    s += __shfl_xor(s, 8, 64);  qs += __shfl_xor(qs, 8, 64);
    const float mean = s * (1.f / 128.f);
    const float var = qs * (1.f / 128.f) - mean * mean;
    const float rs = rsqrtf(var + 1e-5f);
    if (n < N) {
      const float mv = maskV[n];
#pragma unroll
      for (int j = 0; j < 8; ++j) {
        const int col = qq * 8 + j;
        out[(size_t)n * NH + col] = ((vals[j] - mean) * rs * g2[col] + be2[col]) * mv;
      }
    }
  }
}

extern "C" void kernel_launch(void* const* d_in, const int* in_sizes, int n_in,
                              void* d_out, int out_size, void* d_ws, size_t ws_size,
                              hipStream_t stream) {
  const float* hV   = (const float*)d_in[0];
  const float* hE   = (const float*)d_in[1];
  const float* mV   = (const float*)d_in[2];
  const float* mAtt = (const float*)d_in[3];
  const float* W1   = (const float*)d_in[4];
  const float* b1   = (const float*)d_in[5];
  const float* W2   = (const float*)d_in[6];
  const float* b2   = (const float*)d_in[7];
  const float* W3   = (const float*)d_in[8];
  const float* b3   = (const float*)d_in[9];
  const float* g1   = (const float*)d_in[10];
  const float* be1  = (const float*)d_in[11];
  const float* Win  = (const float*)d_in[12];
  const float* binf = (const float*)d_in[13];
  const float* Wout = (const float*)d_in[14];
  const float* bout = (const float*)d_in[15];
  const float* g2   = (const float*)d_in[16];
  const float* be2  = (const float*)d_in[17];

  const int N = in_sizes[0] / NH;

  ushort* wsu = (ushort*)d_ws;                         // packed weights: 448 KB
  float*  hmidf = (float*)((char*)d_ws + 458752);      // N*128 f32
  ushort* hmidb = (ushort*)((char*)d_ws + 458752 + (size_t)N * NH * 4);  // N*128 bf16

  pack_w<<<896, 256, 0, stream>>>(W1, W2, W3, Win, Wout, wsu);

  const int pairs = (N + 1) / 2;
  const int grid = pairs < 512 ? pairs : 512;
  msg7<<<grid, 512, 0, stream>>>(hV, hE, mAtt, wsu, b1, b2, b3, g1, be1,
                                 hmidf, hmidb, N);
  ffn_kernel<<<(N + 15) / 16, 256, 0, stream>>>(wsu, binf, bout, g2, be2, mV,
                                                hmidf, hmidb, (float*)d_out, N);
  (void)n_in; (void)out_size; (void)ws_size;
}

// Round 15
// 164.925 us; speedup vs baseline: 1.6817x; 1.5067x over previous
//
#include <hip/hip_runtime.h>
#include <hip/hip_bf16.h>

#define NH 128   // hidden
#define NC 384   // edge feature dim
#define NK 32    // neighbors

typedef __attribute__((ext_vector_type(8))) short short8v;   // 8 bf16
typedef __attribute__((ext_vector_type(4))) float f32x4;

#define MFMA16(a, b, c) __builtin_amdgcn_mfma_f32_16x16x32_bf16((a), (b), (c), 0, 0, 0)

__device__ __forceinline__ ushort f2bf(float x) {
  __hip_bfloat16 h = __float2bfloat16(x);   // RNE; packs to v_cvt_pk_bf16_f32
  ushort u;
  __builtin_memcpy(&u, &h, 2);
  return u;
}

__device__ __forceinline__ short8v ld8(const ushort* p) {
  return *reinterpret_cast<const short8v*>(p);
}
__device__ __forceinline__ void st8(ushort* p, short8v v) {
  *reinterpret_cast<short8v*>(p) = v;
}

__device__ __forceinline__ short8v pack8(float4 a, float4 b) {
  short8v v;
  v[0] = (short)f2bf(a.x); v[1] = (short)f2bf(a.y);
  v[2] = (short)f2bf(a.z); v[3] = (short)f2bf(a.w);
  v[4] = (short)f2bf(b.x); v[5] = (short)f2bf(b.y);
  v[6] = (short)f2bf(b.z); v[7] = (short)f2bf(b.w);
  return v;
}

// gelu(x) = x * sigmoid(x*(1.5958 + 0.07136 x^2)); |err| vs erf-GELU < 1e-3
__device__ __forceinline__ float gelu_f(float x) {
  float x2 = x * x;
  float m = __builtin_fmaf(0.07135481283f, x2, 1.595769122f);
  float e = __expf(-x * m);
  return x * __builtin_amdgcn_rcpf(1.0f + e);
}

// barrier that does NOT drain vmcnt: LDS writes visible, global loads stay in
// flight. sched_barrier(0) pins codegen around the inline-asm waitcnt (rule 18).
__device__ __forceinline__ void lds_barrier() {
  asm volatile("s_waitcnt lgkmcnt(0)" ::: "memory");
  __builtin_amdgcn_sched_barrier(0);
  __builtin_amdgcn_s_barrier();
}

// ---------------------------------------------------------------------------
// Weight packing: src row-major [k][col] f32 -> bf16 [k/8][col][k%8]
// ushort offsets: W1p 0 (64Ki), W2p 65536 (16Ki), W3p 81920 (16Ki),
// Winp 98304 (64Ki), Woutp 163840 (64Ki). Total 448 KB.
// ---------------------------------------------------------------------------
__global__ __launch_bounds__(256) void pack_w(
    const float* __restrict__ W1, const float* __restrict__ W2,
    const float* __restrict__ W3, const float* __restrict__ Win,
    const float* __restrict__ Wout, ushort* __restrict__ ws) {
  int id = blockIdx.x * 256 + threadIdx.x;
  if (id < 65536) {                       // W1: K=512, ncol=128
    int t = id, k = t >> 7, c = t & 127;
    ws[(((k >> 3) << 7) + c) * 8 + (k & 7)] = f2bf(W1[t]);
  } else if (id < 81920) {                // W2
    int t = id - 65536, k = t >> 7, c = t & 127;
    ws[65536 + (((k >> 3) << 7) + c) * 8 + (k & 7)] = f2bf(W2[t]);
  } else if (id < 98304) {                // W3
    int t = id - 81920, k = t >> 7, c = t & 127;
    ws[81920 + (((k >> 3) << 7) + c) * 8 + (k & 7)] = f2bf(W3[t]);
  } else if (id < 163840) {               // Win: K=128, ncol=512
    int t = id - 98304, k = t >> 9, c = t & 511;
    ws[98304 + (((k >> 3) << 9) + c) * 8 + (k & 7)] = f2bf(Win[t]);
  } else {                                // Wout: K=512, ncol=128
    int t = id - 163840, k = t >> 7, c = t & 127;
    ws[163840 + (((k >> 3) << 7) + c) * 8 + (k & 7)] = f2bf(Wout[t]);
  }
}

// ---------- msg3 helpers (round-8 validated, byte-exact) ----------

// issue global loads of 64-col chunk c of pair p: 8 f32/thread (2 dwordx4)
__device__ __forceinline__ void issue_chunk(const float* __restrict__ hE,
    int p, int c, int tid, int N, float4& a, float4& b) {
  const int r = tid >> 3;              // row 0..63 (node*32 + edge)
  const int cb = (tid & 7) * 8;        // col base within chunk
  const int node = r >> 5, e = r & 31;
  int n = 2 * p + node;
  if (n >= N) n = 0;
  const float* g = hE + ((size_t)n * NK + e) * NC + c * 64 + cb;
  const float4* gp = reinterpret_cast<const float4*>(g);
  a = gp[0];
  b = gp[1];
}

// convert staged regs -> 64x64 bf16 tile (granule XOR-swizzled)
__device__ __forceinline__ void convert_regs(ushort* __restrict__ sC, int tid,
    float4 a, float4 b, bool zz) {
  const int r = tid >> 3, cg = tid & 7;
  short8v v = zz ? (short8v){0, 0, 0, 0, 0, 0, 0, 0} : pack8(a, b);
  st8(sC + r * 64 + ((cg ^ (r & 7)) << 3), v);
}

// MFMA over one 64-col chunk j (k global [128+j*64, 128+(j+1)*64))
__device__ __forceinline__ void mfma_chunk64(const ushort* __restrict__ sC,
    const ushort* __restrict__ W1p, int j, f32x4 acc[4],
    int g, int lr, int outcol) {
#pragma unroll
  for (int jj = 0; jj < 2; ++jj) {
    short8v bfr = ld8(W1p + (((16 + j * 8 + jj * 4 + g) * 128) + outcol) * 8);
    const int akg = jj * 4 + g;
#pragma unroll
    for (int rt = 0; rt < 4; ++rt) {
      const int row = rt * 16 + lr;
      short8v af = ld8(sC + row * 64 + ((akg ^ (row & 7)) << 3));
      acc[rt] = MFMA16(af, bfr, acc[rt]);
    }
  }
}

// 128-wide helpers for H1/H2 (granule space 16, row&15 swizzle)
__device__ __forceinline__ void mfma_chunk(const ushort* __restrict__ buf,
    const ushort* __restrict__ Wp, int ktBase, f32x4 acc[4],
    int g, int lr, int outcol) {
#pragma unroll
  for (int j = 0; j < 4; ++j) {
    short8v bfr = ld8(Wp + (((ktBase + j) * 4 + g) * 128 + outcol) * 8);
    const int kcg = j * 4 + g;
#pragma unroll
    for (int rt = 0; rt < 4; ++rt) {
      const int row = rt * 16 + lr;
      short8v af = ld8(buf + row * 128 + ((kcg ^ (row & 15)) << 3));
      acc[rt] = MFMA16(af, bfr, acc[rt]);
    }
  }
}

__device__ __forceinline__ void epi_store(ushort* __restrict__ buf,
    const f32x4 acc[4], const float* __restrict__ bias, int outcol, int g) {
  const float bs = bias[outcol];
#pragma unroll
  for (int rt = 0; rt < 4; ++rt)
#pragma unroll
    for (int i = 0; i < 4; ++i) {
      const int rr = rt * 16 + g * 4 + i;
      buf[rr * 128 + ((((outcol >> 3) ^ (rr & 15)) << 3) | (outcol & 7))] =
          f2bf(gelu_f(acc[rt][i] + bs));
    }
}

// ---------------------------------------------------------------------------
// Message kernel v3 (round-8 validated, 168us total): one node-pair per
// block, 512 threads, 5000 blocks. 6x64-col chunks, reg-staged (2x8 f32
// banks), lgkm-only barriers keep next-next chunk's loads in flight.
// Fresh blocks (NOT persistent — persistence regressed 4x in rounds 3-14).
// ---------------------------------------------------------------------------
__global__ __launch_bounds__(512, 4) void msg3(
    const float* __restrict__ hV, const float* __restrict__ hE,
    const float* __restrict__ mAtt, const ushort* __restrict__ wsu,
    const float* __restrict__ b1, const float* __restrict__ b2,
    const float* __restrict__ b3, const float* __restrict__ g1,
    const float* __restrict__ be1, float* __restrict__ hmidf,
    ushort* __restrict__ hmidb, int N) {
  const ushort* W1p = wsu;
  const ushort* W2p = wsu + 65536;
  const ushort* W3p = wsu + 81920;

  __shared__ ushort sC[2][4096];    // 2 x 8KB bf16 chunk tiles; reused as H1
  __shared__ ushort sH2[8192];      // 16KB H2
  __shared__ ushort sHV[256];       // 2 nodes x 128 bf16
  __shared__ float  sDh[256];
  __shared__ float  sRed[16];

  const int tid = threadIdx.x;
  const int w = tid >> 6, lane = tid & 63;
  const int g = lane >> 4, lr = lane & 15;
  const int outcol = (w << 4) + lr;
  const int p = blockIdx.x;
  const bool zz = (2 * p + ((tid >> 3) >> 5)) >= N;   // staging-row validity

  float4 eA, eB, oA, oB;   // two 8-f32 staging banks (even/odd chunks)

  // ---- prologue: get memory going immediately ----
  issue_chunk(hE, p, 0, tid, N, eA, eB);
  issue_chunk(hE, p, 1, tid, N, oA, oB);
  if (tid < 32) {
    const int nd = tid >> 4, c8 = tid & 15;
    const int n = 2 * p + nd;
    const int ncl = n < N ? n : 0;
    const float4* hp = reinterpret_cast<const float4*>(hV + (size_t)ncl * NH + c8 * 8);
    float4 h0 = hp[0], h1 = hp[1];
    if (n >= N) { h0 = (float4){0.f, 0.f, 0.f, 0.f}; h1 = h0; }
    st8(sHV + nd * 128 + c8 * 8, pack8(h0, h1));
  }
  convert_regs(sC[0], tid, eA, eB, zz);   // c0 (compiler waits on eA/eB)
  lds_barrier();

  f32x4 acc[4];
#pragma unroll
  for (int rt = 0; rt < 4; ++rt) acc[rt] = (f32x4){0.f, 0.f, 0.f, 0.f};

  // ===== layer-1 hV part (k 0..127, granules 0..15) =====
#pragma unroll
  for (int kt = 0; kt < 4; ++kt) {
    short8v bfr = ld8(W1p + ((kt * 4 + g) * 128 + outcol) * 8);
    short8v a0 = ld8(sHV + kt * 32 + g * 8);
    short8v a1 = ld8(sHV + 128 + kt * 32 + g * 8);
    acc[0] = MFMA16(a0, bfr, acc[0]);
    acc[1] = MFMA16(a0, bfr, acc[1]);
    acc[2] = MFMA16(a1, bfr, acc[2]);
    acc[3] = MFMA16(a1, bfr, acc[3]);
  }

  // ===== layer-1 h_E chunks, software-pipelined =====
  // j=0: consume c0; convert c1; issue c2
  issue_chunk(hE, p, 2, tid, N, eA, eB);
  mfma_chunk64(sC[0], W1p, 0, acc, g, lr, outcol);
  convert_regs(sC[1], tid, oA, oB, zz);
  lds_barrier();
  // j=1: consume c1; convert c2; issue c3
  issue_chunk(hE, p, 3, tid, N, oA, oB);
  mfma_chunk64(sC[1], W1p, 1, acc, g, lr, outcol);
  convert_regs(sC[0], tid, eA, eB, zz);
  lds_barrier();
  // j=2: consume c2; convert c3; issue c4
  issue_chunk(hE, p, 4, tid, N, eA, eB);
  mfma_chunk64(sC[0], W1p, 2, acc, g, lr, outcol);
  convert_regs(sC[1], tid, oA, oB, zz);
  lds_barrier();
  // j=3: consume c3; convert c4; issue c5
  issue_chunk(hE, p, 5, tid, N, oA, oB);
  mfma_chunk64(sC[1], W1p, 3, acc, g, lr, outcol);
  convert_regs(sC[0], tid, eA, eB, zz);
  lds_barrier();
  // j=4: consume c4; convert c5
  mfma_chunk64(sC[0], W1p, 4, acc, g, lr, outcol);
  convert_regs(sC[1], tid, oA, oB, zz);
  lds_barrier();
  // j=5: consume c5
  mfma_chunk64(sC[1], W1p, 5, acc, g, lr, outcol);
  __syncthreads();

  // ===== layer-1 epilogue: H1 -> sC region (as [64][128]) =====
  ushort* sH1 = &sC[0][0];
  epi_store(sH1, acc, b1, outcol, g);
  __syncthreads();

  // ===== layer 2: H1 -> H2 =====
#pragma unroll
  for (int rt = 0; rt < 4; ++rt) acc[rt] = (f32x4){0.f, 0.f, 0.f, 0.f};
  mfma_chunk(sH1, W2p, 0, acc, g, lr, outcol);
  epi_store(sH2, acc, b2, outcol, g);
  __syncthreads();

  // ===== layer 3: H2 -> masked edge-sum =====
#pragma unroll
  for (int rt = 0; rt < 4; ++rt) acc[rt] = (f32x4){0.f, 0.f, 0.f, 0.f};
  mfma_chunk(sH2, W3p, 0, acc, g, lr, outcol);
  {
    const float bias = b3[outcol];
    float ns0 = 0.f, ns1 = 0.f;
#pragma unroll
    for (int rt = 0; rt < 4; ++rt) {
      const int nd = rt >> 1;
      float s = 0.f;
#pragma unroll
      for (int i = 0; i < 4; ++i) {
        const int e2 = (rt & 1) * 16 + g * 4 + i;
        const float m =
            (2 * p + nd < N) ? mAtt[(size_t)(2 * p + nd) * NK + e2] : 0.f;
        s += (acc[rt][i] + bias) * m;
      }
      s += __shfl_xor(s, 16, 64);
      s += __shfl_xor(s, 32, 64);
      if (rt < 2) ns0 += s; else ns1 += s;
    }
    if (g == 0) { sDh[outcol] = ns0; sDh[128 + outcol] = ns1; }
  }
  __syncthreads();

  // ===== LN1 + h_mid store =====
  float x_ln = 0.f;
  if (tid < 256) {
    const int nd = tid >> 7, i = tid & 127;
    const int gn = 2 * p + nd;
    if (gn < N)
      x_ln = hV[(size_t)gn * NH + i] + sDh[nd * NH + i] * (1.f / 30.f);
    float s = x_ln, qv = x_ln * x_ln;
#pragma unroll
    for (int d = 1; d < 64; d <<= 1) {
      s += __shfl_xor(s, d, 64);
      qv += __shfl_xor(qv, d, 64);
    }
    if (lane == 0) { sRed[w * 2] = s; sRed[w * 2 + 1] = qv; }
  }
  __syncthreads();
  if (tid < 256) {
    const int nd = tid >> 7, i = tid & 127;
    const int gn = 2 * p + nd;
    if (gn < N) {
      const int wb = nd * 2;
      const float s = sRed[wb * 2] + sRed[wb * 2 + 2];
      const float qv = sRed[wb * 2 + 1] + sRed[wb * 2 + 3];
      const float mean = s * (1.f / 128.f);
      const float var = qv * (1.f / 128.f) - mean * mean;
      const float y = (x_ln - mean) * rsqrtf(var + 1e-5f) * g1[i] + be1[i];
      hmidf[(size_t)gn * NH + i] = y;
      hmidb[(size_t)gn * NH + i] = f2bf(y);
    }
  }
}

// ---------------------------------------------------------------------------
// FFN kernel v2: 32 nodes / block (313 blocks), 512 threads (8 waves).
// Halves L2 weight traffic vs 16-node version (each block reads the full
// 256KB packed Win/Wout once for 32 rows instead of 16).
// LDS: sX 8KB + sHf 32KB + sY 16.9KB = ~57KB -> 2 blocks/CU.
// ---------------------------------------------------------------------------
__global__ __launch_bounds__(512, 4) void ffn32(
    const ushort* __restrict__ wsu, const float* __restrict__ binf,
    const float* __restrict__ boutf, const float* __restrict__ g2,
    const float* __restrict__ be2, const float* __restrict__ maskV,
    const float* __restrict__ hmidf, const ushort* __restrict__ hmidb,
    float* __restrict__ out, int N) {
  const ushort* Winp = wsu + 98304;
  const ushort* Woutp = wsu + 163840;

  __shared__ ushort sX[32 * 128];     // 8KB
  __shared__ ushort sHf[32 * 512];    // 32KB
  __shared__ float  sY[32 * 132];     // 16.9KB

  const int tid = threadIdx.x;
  const int w = tid >> 6, lane = tid & 63;
  const int g = lane >> 4, lr = lane & 15;
  const int n0 = blockIdx.x * 32;

  // stage h_mid (bf16) -> sX swizzled (512 chunks, one per thread)
  {
    const int rr = tid >> 4, c8 = tid & 15;
    const int n = n0 + rr;
    short8v v = {0, 0, 0, 0, 0, 0, 0, 0};
    if (n < N) v = ld8(hmidb + (size_t)n * NH + c8 * 8);
    st8(sX + rr * 128 + ((c8 ^ (rr & 15)) << 3), v);
  }
  __syncthreads();

  // -------- layer in: [32,128] @ Win -> gelu -> sHf [32,512] --------
  // wave w owns cols [w*64, w*64+64): 4 col-tiles; a-frags reused across them
  {
    f32x4 accI[4][2];
#pragma unroll
    for (int ct = 0; ct < 4; ++ct) {
      accI[ct][0] = (f32x4){0.f, 0.f, 0.f, 0.f};
      accI[ct][1] = accI[ct][0];
    }
#pragma unroll
    for (int kt = 0; kt < 4; ++kt) {
      const int kcg = kt * 4 + g;
      short8v a0 = ld8(sX + lr * 128 + ((kcg ^ lr) << 3));
      short8v a1 = ld8(sX + (16 + lr) * 128 + ((kcg ^ lr) << 3));
#pragma unroll
      for (int ct = 0; ct < 4; ++ct) {
        const int col = (w << 6) + ct * 16 + lr;
        short8v b = ld8(Winp + (kcg * 512 + col) * 8);
        accI[ct][0] = MFMA16(a0, b, accI[ct][0]);
        accI[ct][1] = MFMA16(a1, b, accI[ct][1]);
      }
    }
#pragma unroll
    for (int ct = 0; ct < 4; ++ct) {
      const int col = (w << 6) + ct * 16 + lr;
      const float bi = binf[col];
      const int c8 = col >> 3;
#pragma unroll
      for (int rt = 0; rt < 2; ++rt)
#pragma unroll
        for (int i = 0; i < 4; ++i) {
          const int rr = rt * 16 + g * 4 + i;
          sHf[rr * 512 + (((c8 ^ (rr & 15)) << 3) | (col & 7))] =
              f2bf(gelu_f(accI[ct][rt][i] + bi));
        }
    }
  }
  __syncthreads();

  // -------- layer out: [32,512] @ Wout (wave w -> cols [w*16, w*16+16)) ----
  f32x4 o0 = (f32x4){0.f, 0.f, 0.f, 0.f}, o1 = o0;
  const int ocol = (w << 4) + lr;
#pragma unroll
  for (int kt = 0; kt < 16; ++kt) {
    const int kcg = kt * 4 + g;                 // [0,64)
    short8v b = ld8(Woutp + (kcg * 128 + ocol) * 8);
    short8v a0 = ld8(sHf + lr * 512 + ((kcg ^ lr) << 3));
    short8v a1 = ld8(sHf + (16 + lr) * 512 + ((kcg ^ lr) << 3));
    o0 = MFMA16(a0, b, o0);
    o1 = MFMA16(a1, b, o1);
  }
  // epilogue: + bias + residual -> sY
  {
    const float bo = boutf[ocol];
#pragma unroll
    for (int rt = 0; rt < 2; ++rt) {
      const f32x4 oo = rt ? o1 : o0;
#pragma unroll
      for (int i = 0; i < 4; ++i) {
        const int rr = rt * 16 + g * 4 + i;
        const int n = n0 + rr;
        const float resid = (n < N) ? hmidf[(size_t)n * NH + ocol] : 0.f;
        sY[rr * 132 + ocol] = oo[i] + bo + resid;
      }
    }
  }
  __syncthreads();

  // -------- LN2 + mask + store (16 threads per row, 8 cols each) --------
  {
    const int rr = tid >> 4, qq = tid & 15;
    const int n = n0 + rr;
    float vals[8];
    float s = 0.f, qs = 0.f;
    const float* yr = sY + rr * 132 + qq * 8;
#pragma unroll
    for (int j = 0; j < 8; ++j) { float x = yr[j]; vals[j] = x; s += x; qs += x * x; }
    s += __shfl_xor(s, 1, 64);  qs += __shfl_xor(qs, 1, 64);
    s += __shfl_xor(s, 2, 64);  qs += __shfl_xor(qs, 2, 64);
    s += __shfl_xor(s, 4, 64);  qs += __shfl_xor(qs, 4, 64);
    s += __shfl_xor(s, 8, 64);  qs += __shfl_xor(qs, 8, 64);
    const float mean = s * (1.f / 128.f);
    const float var = qs * (1.f / 128.f) - mean * mean;
    const float rs = rsqrtf(var + 1e-5f);
    if (n < N) {
      const float mv = maskV[n];
#pragma unroll
      for (int j = 0; j < 8; ++j) {
        const int col = qq * 8 + j;
        out[(size_t)n * NH + col] = ((vals[j] - mean) * rs * g2[col] + be2[col]) * mv;
      }
    }
  }
}

extern "C" void kernel_launch(void* const* d_in, const int* in_sizes, int n_in,
                              void* d_out, int out_size, void* d_ws, size_t ws_size,
                              hipStream_t stream) {
  const float* hV   = (const float*)d_in[0];
  const float* hE   = (const float*)d_in[1];
  const float* mV   = (const float*)d_in[2];
  const float* mAtt = (const float*)d_in[3];
  const float* W1   = (const float*)d_in[4];
  const float* b1   = (const float*)d_in[5];
  const float* W2   = (const float*)d_in[6];
  const float* b2   = (const float*)d_in[7];
  const float* W3   = (const float*)d_in[8];
  const float* b3   = (const float*)d_in[9];
  const float* g1   = (const float*)d_in[10];
  const float* be1  = (const float*)d_in[11];
  const float* Win  = (const float*)d_in[12];
  const float* binf = (const float*)d_in[13];
  const float* Wout = (const float*)d_in[14];
  const float* bout = (const float*)d_in[15];
  const float* g2   = (const float*)d_in[16];
  const float* be2  = (const float*)d_in[17];

  const int N = in_sizes[0] / NH;

  ushort* wsu = (ushort*)d_ws;                         // packed weights: 448 KB
  float*  hmidf = (float*)((char*)d_ws + 458752);      // N*128 f32
  ushort* hmidb = (ushort*)((char*)d_ws + 458752 + (size_t)N * NH * 4);  // N*128 bf16

  pack_w<<<896, 256, 0, stream>>>(W1, W2, W3, Win, Wout, wsu);

  const int pairs = (N + 1) / 2;
  msg3<<<pairs, 512, 0, stream>>>(hV, hE, mAtt, wsu, b1, b2, b3, g1, be1,
                                  hmidf, hmidb, N);
  ffn32<<<(N + 31) / 32, 512, 0, stream>>>(wsu, binf, bout, g2, be2, mV,
                                           hmidf, hmidb, (float*)d_out, N);
  (void)n_in; (void)out_size; (void)ws_size;
}